// Round 1
// baseline (1409.115 us; speedup 1.0000x reference)
//
#include <hip/hip_runtime.h>

#define T_SEQ 512
#define HID 64
#define NG 256            // 4*HID gate rows
#define MB 16             // batch rows per block
#define NTHREADS 512
// A1 K-layout (K1=224, 7 MFMA K-steps):
//   [0,64)  h1_hi   [64,128) h1_lo   [128,192) h1_hi(repeat, pairs W_lo)
//   [192,199) x_hi  [199,206) x_lo   [206,213) x_hi(repeat)  [213,224) zero
// A2 K-layout (K2=384, 12 K-steps):
//   [0,64) h1c_hi [64,128) h1c_lo [128,192) h1c_hi
//   [192,256) h2_hi [256,320) h2_lo [320,384) h2_hi
#define A1STR 232   // padded LDS row stride (bank-conflict: 2-way only)
#define A2STR 392
#define GSTR  260

typedef __attribute__((ext_vector_type(8))) short short8;
typedef __attribute__((ext_vector_type(4))) float floatx4;

__device__ __forceinline__ short f2bf(float v) {
  unsigned u = __float_as_uint(v);
  unsigned r = (u + 0x7FFFu + ((u >> 16) & 1u)) >> 16;   // RNE
  return (short)r;
}
__device__ __forceinline__ float bf2f(short b) {
  return __uint_as_float(((unsigned)(unsigned short)b) << 16);
}
__device__ __forceinline__ float sigm(float x) { return 1.f / (1.f + __expf(-x)); }
__device__ __forceinline__ float tanh_(float x) { return 1.f - 2.f / (__expf(2.f * x) + 1.f); }

// B1[k][n] element for layer-1 concatenated weight matrix (bf16 bits)
__device__ __forceinline__ short w1elem(int k, int n, const float* __restrict__ Wih0,
                                        const float* __restrict__ Whh0) {
  float v; bool lo = false;
  if      (k < 64)  { v = Whh0[n*64 + k]; }
  else if (k < 128) { v = Whh0[n*64 + (k-64)]; }
  else if (k < 192) { v = Whh0[n*64 + (k-128)]; lo = true; }
  else if (k < 199) { v = Wih0[n*7 + (k-192)]; }
  else if (k < 206) { v = Wih0[n*7 + (k-199)]; }
  else if (k < 213) { v = Wih0[n*7 + (k-206)]; lo = true; }
  else return (short)0;
  short h = f2bf(v);
  if (!lo) return h;
  return f2bf(v - bf2f(h));
}
__device__ __forceinline__ short w2elem(int k, int n, const float* __restrict__ Wih1,
                                        const float* __restrict__ Whh1) {
  float v; bool lo = false;
  if      (k < 64)  { v = Wih1[n*64 + k]; }
  else if (k < 128) { v = Wih1[n*64 + (k-64)]; }
  else if (k < 192) { v = Wih1[n*64 + (k-128)]; lo = true; }
  else if (k < 256) { v = Whh1[n*64 + (k-192)]; }
  else if (k < 320) { v = Whh1[n*64 + (k-256)]; }
  else              { v = Whh1[n*64 + (k-320)]; lo = true; }
  short h = f2bf(v);
  if (!lo) return h;
  return f2bf(v - bf2f(h));
}

__global__ __launch_bounds__(NTHREADS, 2) void lstm_fused(
    const float* __restrict__ x,
    const float* __restrict__ Wih0, const float* __restrict__ Whh0,
    const float* __restrict__ bih0, const float* __restrict__ bhh0,
    const float* __restrict__ Wih1, const float* __restrict__ Whh1,
    const float* __restrict__ bih1, const float* __restrict__ bhh1,
    const float* __restrict__ Wfc,  const float* __restrict__ bfc,
    float* __restrict__ out)
{
  __shared__ __align__(16) short A1[MB][A1STR];
  __shared__ __align__(16) short A2[MB][A2STR];
  __shared__ __align__(16) float gatesS[2][MB][GSTR];
  __shared__ float biasS[2][NG];
  __shared__ float h2f[MB][HID + 4];

  const int tid  = threadIdx.x;
  const int lane = tid & 63;
  const int wave = tid >> 6;
  const int l15  = lane & 15;
  const int quad = lane >> 4;
  const int b0   = blockIdx.x * MB;

  // ---- init: zero A-staging, build biases, stage x(0) ----
  for (int i = tid; i < MB*A1STR/2; i += NTHREADS) ((unsigned*)A1)[i] = 0u;
  for (int i = tid; i < MB*A2STR/2; i += NTHREADS) ((unsigned*)A2)[i] = 0u;
  if (tid < NG) {
    biasS[0][tid] = bih0[tid] + bhh0[tid];
    biasS[1][tid] = bih1[tid] + bhh1[tid];
  }
  if (tid < MB*7) {
    int bb = tid / 7, d = tid % 7;
    float xv = x[((size_t)(b0 + bb) * T_SEQ + 0) * 7 + d];
    short xh = f2bf(xv); short xl = f2bf(xv - bf2f(xh));
    A1[bb][192 + d] = xh; A1[bb][199 + d] = xl; A1[bb][206 + d] = xh;
  }

  // ---- load weight B-fragments into registers (held across all 512 steps) ----
  short8 B1f[7][2];
  short8 B2f[12][2];
  #pragma unroll
  for (int ks = 0; ks < 7; ++ks)
    #pragma unroll
    for (int i = 0; i < 2; ++i) {
      short8 f;
      const int n = wave*32 + i*16 + l15;
      #pragma unroll
      for (int j = 0; j < 8; ++j) f[j] = w1elem(ks*32 + quad*8 + j, n, Wih0, Whh0);
      B1f[ks][i] = f;
    }
  #pragma unroll
  for (int ks = 0; ks < 12; ++ks)
    #pragma unroll
    for (int i = 0; i < 2; ++i) {
      short8 f;
      const int n = wave*32 + i*16 + l15;
      #pragma unroll
      for (int j = 0; j < 8; ++j) f[j] = w2elem(ks*32 + quad*8 + j, n, Wih1, Whh1);
      B2f[ks][i] = f;
    }
  __syncthreads();

  float c1[2] = {0.f, 0.f}, c2[2] = {0.f, 0.f};
  const int bb = tid >> 5;      // batch row for elementwise phase
  const int jp = tid & 31;      // unit-pair index
  const int j0 = jp * 2;

  // Pipelined: iteration it does GEMM1(it) and GEMM2(it-1), then elementwise.
  for (int it = 0; it <= T_SEQ; ++it) {
    // ---- phase A: MFMA GEMMs ----
    if (it < T_SEQ) {
      floatx4 a0 = {0.f,0.f,0.f,0.f}, a1 = {0.f,0.f,0.f,0.f};
      #pragma unroll
      for (int ks = 0; ks < 7; ++ks) {
        short8 af = *(const short8*)&A1[l15][ks*32 + quad*8];
        a0 = __builtin_amdgcn_mfma_f32_16x16x32_bf16(af, B1f[ks][0], a0, 0, 0, 0);
        a1 = __builtin_amdgcn_mfma_f32_16x16x32_bf16(af, B1f[ks][1], a1, 0, 0, 0);
      }
      #pragma unroll
      for (int r = 0; r < 4; ++r) {
        gatesS[0][quad*4 + r][wave*32 + l15]      = a0[r];
        gatesS[0][quad*4 + r][wave*32 + 16 + l15] = a1[r];
      }
    }
    if (it >= 1) {
      floatx4 a0 = {0.f,0.f,0.f,0.f}, a1 = {0.f,0.f,0.f,0.f};
      #pragma unroll
      for (int ks = 0; ks < 12; ++ks) {
        short8 af = *(const short8*)&A2[l15][ks*32 + quad*8];
        a0 = __builtin_amdgcn_mfma_f32_16x16x32_bf16(af, B2f[ks][0], a0, 0, 0, 0);
        a1 = __builtin_amdgcn_mfma_f32_16x16x32_bf16(af, B2f[ks][1], a1, 0, 0, 0);
      }
      #pragma unroll
      for (int r = 0; r < 4; ++r) {
        gatesS[1][quad*4 + r][wave*32 + l15]      = a0[r];
        gatesS[1][quad*4 + r][wave*32 + 16 + l15] = a1[r];
      }
    }
    __syncthreads();

    // ---- phase B: elementwise LSTM updates ----
    if (it < T_SEQ) {   // layer-1 update for step `it`
      float hh[2];
      #pragma unroll
      for (int u = 0; u < 2; ++u) {
        int j = j0 + u;
        float gi = gatesS[0][bb][j]       + biasS[0][j];
        float gf = gatesS[0][bb][64 + j]  + biasS[0][64 + j];
        float gg = gatesS[0][bb][128 + j] + biasS[0][128 + j];
        float go = gatesS[0][bb][192 + j] + biasS[0][192 + j];
        float iv = sigm(gi), fv = sigm(gf), gv = tanh_(gg), ov = sigm(go);
        c1[u] = fv * c1[u] + iv * gv;
        hh[u] = ov * tanh_(c1[u]);
      }
      short h0 = f2bf(hh[0]); short l0 = f2bf(hh[0] - bf2f(h0));
      short h1 = f2bf(hh[1]); short l1 = f2bf(hh[1] - bf2f(h1));
      unsigned hp = (unsigned)(unsigned short)h0 | ((unsigned)(unsigned short)h1 << 16);
      unsigned lp = (unsigned)(unsigned short)l0 | ((unsigned)(unsigned short)l1 << 16);
      *(unsigned*)&A1[bb][j0]        = hp;
      *(unsigned*)&A1[bb][64 + j0]   = lp;
      *(unsigned*)&A1[bb][128 + j0]  = hp;
      *(unsigned*)&A2[bb][j0]        = hp;
      *(unsigned*)&A2[bb][64 + j0]   = lp;
      *(unsigned*)&A2[bb][128 + j0]  = hp;
    }
    if (it >= 1) {      // layer-2 update for step `it-1`
      float hh[2];
      #pragma unroll
      for (int u = 0; u < 2; ++u) {
        int j = j0 + u;
        float gi = gatesS[1][bb][j]       + biasS[1][j];
        float gf = gatesS[1][bb][64 + j]  + biasS[1][64 + j];
        float gg = gatesS[1][bb][128 + j] + biasS[1][128 + j];
        float go = gatesS[1][bb][192 + j] + biasS[1][192 + j];
        float iv = sigm(gi), fv = sigm(gf), gv = tanh_(gg), ov = sigm(go);
        c2[u] = fv * c2[u] + iv * gv;
        hh[u] = ov * tanh_(c2[u]);
      }
      if (it == T_SEQ) { h2f[bb][j0] = hh[0]; h2f[bb][j0 + 1] = hh[1]; }
      short h0 = f2bf(hh[0]); short l0 = f2bf(hh[0] - bf2f(h0));
      short h1 = f2bf(hh[1]); short l1 = f2bf(hh[1] - bf2f(h1));
      unsigned hp = (unsigned)(unsigned short)h0 | ((unsigned)(unsigned short)h1 << 16);
      unsigned lp = (unsigned)(unsigned short)l0 | ((unsigned)(unsigned short)l1 << 16);
      *(unsigned*)&A2[bb][192 + j0] = hp;
      *(unsigned*)&A2[bb][256 + j0] = lp;
      *(unsigned*)&A2[bb][320 + j0] = hp;
    }
    if (it < T_SEQ - 1 && tid < MB*7) {   // prefetch x(it+1) into A1
      int bbx = tid / 7, d = tid % 7;
      float xv = x[((size_t)(b0 + bbx) * T_SEQ + (it + 1)) * 7 + d];
      short xh = f2bf(xv); short xl = f2bf(xv - bf2f(xh));
      A1[bbx][192 + d] = xh; A1[bbx][199 + d] = xl; A1[bbx][206 + d] = xh;
    }
    __syncthreads();
  }

  // ---- final FC: out[b,o] = h2(T-1)[b,:] . Wfc[o,:] + bfc[o] ----
  if (tid < MB * 4) {
    int bbf = tid >> 2, o = tid & 3;
    float acc = bfc[o];
    #pragma unroll 8
    for (int k = 0; k < HID; ++k) acc += h2f[bbf][k] * Wfc[o*HID + k];
    out[(size_t)(b0 + bbf) * 4 + o] = acc;
  }
}

extern "C" void kernel_launch(void* const* d_in, const int* in_sizes, int n_in,
                              void* d_out, int out_size, void* d_ws, size_t ws_size,
                              hipStream_t stream) {
  const float* x    = (const float*)d_in[0];
  const float* Wih0 = (const float*)d_in[1];
  const float* Whh0 = (const float*)d_in[2];
  const float* bih0 = (const float*)d_in[3];
  const float* bhh0 = (const float*)d_in[4];
  const float* Wih1 = (const float*)d_in[5];
  const float* Whh1 = (const float*)d_in[6];
  const float* bih1 = (const float*)d_in[7];
  const float* bhh1 = (const float*)d_in[8];
  const float* Wfc  = (const float*)d_in[9];
  const float* bfc  = (const float*)d_in[10];
  (void)d_ws; (void)ws_size; (void)n_in; (void)out_size;

  const int B = in_sizes[0] / (T_SEQ * 7);   // 4096
  dim3 grid(B / MB);
  lstm_fused<<<grid, NTHREADS, 0, stream>>>(x, Wih0, Whh0, bih0, bhh0,
                                            Wih1, Whh1, bih1, bhh1, Wfc, bfc,
                                            (float*)d_out);
}

// Round 2
// 976.580 us; speedup vs baseline: 1.4429x; 1.4429x over previous
//
#include <hip/hip_runtime.h>

#define T_SEQ 512
#define HID 64
#define MB 16             // batch rows per block
#define NTHREADS 512
// A1 K-layout (K1=224, 7 MFMA ksteps; ksteps 4,5 reuse regs of 0,1):
//   [0,64) h1_hi  [64,128) h1_lo  [128,192) UNUSED (W_lo pairs reuse h1_hi regs)
//   [192,199) x_hi [199,206) x_lo [206,213) x_hi(dup, intra-kstep) [213,224) zero
// A2 K-layout (LDS stores 256; 12 MFMA ksteps, 8 LDS reads):
//   [0,64) h1_hi [64,128) h1_lo [128,192) h2_hi [192,256) h2_lo
#define A1STR 232   // shorts; 116 dwords -> uniform bank-group spread
#define A2STR 264   // shorts; 132 dwords
#define GSTR  260   // floats

typedef __attribute__((ext_vector_type(8))) short short8;
typedef __attribute__((ext_vector_type(4))) float floatx4;

__device__ __forceinline__ short f2bf(float v) {
  unsigned u = __float_as_uint(v);
  unsigned r = (u + 0x7FFFu + ((u >> 16) & 1u)) >> 16;   // RNE
  return (short)r;
}
__device__ __forceinline__ float bf2f(short b) {
  return __uint_as_float(((unsigned)(unsigned short)b) << 16);
}
__device__ __forceinline__ float rcp_(float x) { return __builtin_amdgcn_rcpf(x); }
__device__ __forceinline__ float sigm(float x) {
  return rcp_(1.f + __builtin_amdgcn_exp2f(-1.4426950408889634f * x));
}
__device__ __forceinline__ float tanh_(float x) {
  return 1.f - 2.f * rcp_(__builtin_amdgcn_exp2f(2.8853900817779268f * x) + 1.f);
}

// B1[k][n] element for layer-1 concatenated weight matrix (bf16 bits)
__device__ __forceinline__ short w1elem(int k, int n, const float* __restrict__ Wih0,
                                        const float* __restrict__ Whh0) {
  float v; bool lo = false;
  if      (k < 64)  { v = Whh0[n*64 + k]; }
  else if (k < 128) { v = Whh0[n*64 + (k-64)]; }
  else if (k < 192) { v = Whh0[n*64 + (k-128)]; lo = true; }
  else if (k < 199) { v = Wih0[n*7 + (k-192)]; }
  else if (k < 206) { v = Wih0[n*7 + (k-199)]; }
  else if (k < 213) { v = Wih0[n*7 + (k-206)]; lo = true; }
  else return (short)0;
  short h = f2bf(v);
  if (!lo) return h;
  return f2bf(v - bf2f(h));
}
__device__ __forceinline__ short w2elem(int k, int n, const float* __restrict__ Wih1,
                                        const float* __restrict__ Whh1) {
  float v; bool lo = false;
  if      (k < 64)  { v = Wih1[n*64 + k]; }
  else if (k < 128) { v = Wih1[n*64 + (k-64)]; }
  else if (k < 192) { v = Wih1[n*64 + (k-128)]; lo = true; }
  else if (k < 256) { v = Whh1[n*64 + (k-192)]; }
  else if (k < 320) { v = Whh1[n*64 + (k-256)]; }
  else              { v = Whh1[n*64 + (k-320)]; lo = true; }
  short h = f2bf(v);
  if (!lo) return h;
  return f2bf(v - bf2f(h));
}

#define MFMA(A, B, C) __builtin_amdgcn_mfma_f32_16x16x32_bf16((A), (B), (C), 0, 0, 0)

__global__ __launch_bounds__(NTHREADS, 2) void lstm_fused(
    const float* __restrict__ x,
    const float* __restrict__ Wih0, const float* __restrict__ Whh0,
    const float* __restrict__ bih0, const float* __restrict__ bhh0,
    const float* __restrict__ Wih1, const float* __restrict__ Whh1,
    const float* __restrict__ bih1, const float* __restrict__ bhh1,
    const float* __restrict__ Wfc,  const float* __restrict__ bfc,
    float* __restrict__ out)
{
  __shared__ __align__(16) short A1[MB][A1STR];
  __shared__ __align__(16) short A2[MB][A2STR];
  __shared__ __align__(16) float gatesS[2][MB][GSTR];
  __shared__ float h2f[MB][HID + 4];

  const int tid  = threadIdx.x;
  const int lane = tid & 63;
  const int wave = tid >> 6;
  const int l15  = lane & 15;
  const int quad = lane >> 4;
  const int b0   = blockIdx.x * MB;
  const int j    = tid & 63;     // unit index for elementwise phase
  const int r0   = tid >> 6;     // first batch row for elementwise phase

  // ---- init: zero A-staging ----
  for (int i = tid; i < MB*A1STR/2; i += NTHREADS) ((unsigned*)A1)[i] = 0u;
  for (int i = tid; i < MB*A2STR/2; i += NTHREADS) ((unsigned*)A2)[i] = 0u;

  // ---- biases into registers (per-thread, fixed unit j) ----
  float b1g[4], b2g[4];
  #pragma unroll
  for (int g = 0; g < 4; ++g) {
    b1g[g] = bih0[g*64 + j] + bhh0[g*64 + j];
    b2g[g] = bih1[g*64 + j] + bhh1[g*64 + j];
  }

  // ---- stage x(0); preload x(1) into register pipeline ----
  const int xb = tid / 7, xd = tid - xb * 7;
  float xcur = 0.f;
  if (tid < 112) {
    float xv = x[((size_t)(b0 + xb) * T_SEQ + 0) * 7 + xd];
    short xh = f2bf(xv); short xl = f2bf(xv - bf2f(xh));
    A1[xb][192 + xd] = xh; A1[xb][199 + xd] = xl; A1[xb][206 + xd] = xh;
    xcur = x[((size_t)(b0 + xb) * T_SEQ + 1) * 7 + xd];
  }

  // ---- weight B-fragments in registers (held across all 512 steps) ----
  short8 B1f[7][2];
  short8 B2f[12][2];
  #pragma unroll
  for (int ks = 0; ks < 7; ++ks)
    #pragma unroll
    for (int i = 0; i < 2; ++i) {
      short8 f;
      const int n = wave*32 + i*16 + l15;
      #pragma unroll
      for (int jj = 0; jj < 8; ++jj) f[jj] = w1elem(ks*32 + quad*8 + jj, n, Wih0, Whh0);
      B1f[ks][i] = f;
    }
  #pragma unroll
  for (int ks = 0; ks < 12; ++ks)
    #pragma unroll
    for (int i = 0; i < 2; ++i) {
      short8 f;
      const int n = wave*32 + i*16 + l15;
      #pragma unroll
      for (int jj = 0; jj < 8; ++jj) f[jj] = w2elem(ks*32 + quad*8 + jj, n, Wih1, Whh1);
      B2f[ks][i] = f;
    }
  __syncthreads();

  float c1[2] = {0.f, 0.f}, c2[2] = {0.f, 0.f};
  float xnext = 0.f;

  // Pipelined: iteration it does GEMM1(it) and GEMM2(it-1), then elementwise.
  for (int it = 0; it <= T_SEQ; ++it) {
    // issue next x load EARLY so the pre-barrier vmcnt drain doesn't stall
    if (tid < 112 && it + 2 < T_SEQ)
      xnext = x[((size_t)(b0 + xb) * T_SEQ + (it + 2)) * 7 + xd];

    // ---- phase A: MFMA GEMMs ----
    if (it < T_SEQ) {
      short8 af0 = *(const short8*)&A1[l15][      quad*8];
      short8 af1 = *(const short8*)&A1[l15][ 32 + quad*8];
      short8 af2 = *(const short8*)&A1[l15][ 64 + quad*8];
      short8 af3 = *(const short8*)&A1[l15][ 96 + quad*8];
      short8 af6 = *(const short8*)&A1[l15][192 + quad*8];
      floatx4 a0 = {0.f,0.f,0.f,0.f}, a1v = {0.f,0.f,0.f,0.f};
      a0 = MFMA(af0, B1f[0][0], a0);  a1v = MFMA(af0, B1f[0][1], a1v);
      a0 = MFMA(af1, B1f[1][0], a0);  a1v = MFMA(af1, B1f[1][1], a1v);
      a0 = MFMA(af2, B1f[2][0], a0);  a1v = MFMA(af2, B1f[2][1], a1v);
      a0 = MFMA(af3, B1f[3][0], a0);  a1v = MFMA(af3, B1f[3][1], a1v);
      a0 = MFMA(af0, B1f[4][0], a0);  a1v = MFMA(af0, B1f[4][1], a1v);  // h_hi x W_lo
      a0 = MFMA(af1, B1f[5][0], a0);  a1v = MFMA(af1, B1f[5][1], a1v);  // h_hi x W_lo
      a0 = MFMA(af6, B1f[6][0], a0);  a1v = MFMA(af6, B1f[6][1], a1v);  // x block
      #pragma unroll
      for (int r = 0; r < 4; ++r) {
        gatesS[0][quad*4 + r][wave*32 + l15]      = a0[r];
        gatesS[0][quad*4 + r][wave*32 + 16 + l15] = a1v[r];
      }
    }
    if (it >= 1) {
      short8 g0 = *(const short8*)&A2[l15][      quad*8];
      short8 g1 = *(const short8*)&A2[l15][ 32 + quad*8];
      short8 g2 = *(const short8*)&A2[l15][ 64 + quad*8];
      short8 g3 = *(const short8*)&A2[l15][ 96 + quad*8];
      short8 g4 = *(const short8*)&A2[l15][128 + quad*8];
      short8 g5 = *(const short8*)&A2[l15][160 + quad*8];
      short8 g6 = *(const short8*)&A2[l15][192 + quad*8];
      short8 g7 = *(const short8*)&A2[l15][224 + quad*8];
      floatx4 a0 = {0.f,0.f,0.f,0.f}, a1v = {0.f,0.f,0.f,0.f};
      a0 = MFMA(g0, B2f[0][0],  a0);  a1v = MFMA(g0, B2f[0][1],  a1v);
      a0 = MFMA(g1, B2f[1][0],  a0);  a1v = MFMA(g1, B2f[1][1],  a1v);
      a0 = MFMA(g2, B2f[2][0],  a0);  a1v = MFMA(g2, B2f[2][1],  a1v);
      a0 = MFMA(g3, B2f[3][0],  a0);  a1v = MFMA(g3, B2f[3][1],  a1v);
      a0 = MFMA(g0, B2f[4][0],  a0);  a1v = MFMA(g0, B2f[4][1],  a1v);  // h1_hi x W_lo
      a0 = MFMA(g1, B2f[5][0],  a0);  a1v = MFMA(g1, B2f[5][1],  a1v);
      a0 = MFMA(g4, B2f[6][0],  a0);  a1v = MFMA(g4, B2f[6][1],  a1v);  // h2_hi x W_hi
      a0 = MFMA(g5, B2f[7][0],  a0);  a1v = MFMA(g5, B2f[7][1],  a1v);
      a0 = MFMA(g6, B2f[8][0],  a0);  a1v = MFMA(g6, B2f[8][1],  a1v);  // h2_lo x W_hi
      a0 = MFMA(g7, B2f[9][0],  a0);  a1v = MFMA(g7, B2f[9][1],  a1v);
      a0 = MFMA(g4, B2f[10][0], a0);  a1v = MFMA(g4, B2f[10][1], a1v);  // h2_hi x W_lo
      a0 = MFMA(g5, B2f[11][0], a0);  a1v = MFMA(g5, B2f[11][1], a1v);
      #pragma unroll
      for (int r = 0; r < 4; ++r) {
        gatesS[1][quad*4 + r][wave*32 + l15]      = a0[r];
        gatesS[1][quad*4 + r][wave*32 + 16 + l15] = a1v[r];
      }
    }
    __syncthreads();

    // ---- phase B: elementwise LSTM updates (unit-major: stride-1 LDS) ----
    if (it < T_SEQ) {   // layer-1 update for step `it`
      #pragma unroll
      for (int p = 0; p < 2; ++p) {
        const int r = r0 + 8*p;
        float gi = gatesS[0][r][j]       + b1g[0];
        float gf = gatesS[0][r][64 + j]  + b1g[1];
        float gg = gatesS[0][r][128 + j] + b1g[2];
        float go = gatesS[0][r][192 + j] + b1g[3];
        float iv = sigm(gi), fv = sigm(gf), gv = tanh_(gg), ov = sigm(go);
        c1[p] = fv * c1[p] + iv * gv;
        float h = ov * tanh_(c1[p]);
        short hh = f2bf(h); short hl = f2bf(h - bf2f(hh));
        A1[r][j] = hh;  A1[r][64 + j] = hl;
        A2[r][j] = hh;  A2[r][64 + j] = hl;
      }
    }
    if (it >= 1) {      // layer-2 update for step `it-1`
      #pragma unroll
      for (int p = 0; p < 2; ++p) {
        const int r = r0 + 8*p;
        float gi = gatesS[1][r][j]       + b2g[0];
        float gf = gatesS[1][r][64 + j]  + b2g[1];
        float gg = gatesS[1][r][128 + j] + b2g[2];
        float go = gatesS[1][r][192 + j] + b2g[3];
        float iv = sigm(gi), fv = sigm(gf), gv = tanh_(gg), ov = sigm(go);
        c2[p] = fv * c2[p] + iv * gv;
        float h = ov * tanh_(c2[p]);
        if (it == T_SEQ) h2f[r][j] = h;
        short hh = f2bf(h); short hl = f2bf(h - bf2f(hh));
        A2[r][128 + j] = hh;  A2[r][192 + j] = hl;
      }
    }
    if (tid < 112 && it + 1 < T_SEQ) {   // stage x(it+1), loaded one iter ago
      short xh = f2bf(xcur); short xl = f2bf(xcur - bf2f(xh));
      A1[xb][192 + xd] = xh; A1[xb][199 + xd] = xl; A1[xb][206 + xd] = xh;
      xcur = xnext;
    }
    __syncthreads();
  }

  // ---- final FC: out[b,o] = h2(T-1)[b,:] . Wfc[o,:] + bfc[o] ----
  if (tid < MB * 4) {
    int bbf = tid >> 2, o = tid & 3;
    float acc = bfc[o];
    #pragma unroll 8
    for (int k = 0; k < HID; ++k) acc += h2f[bbf][k] * Wfc[o*HID + k];
    out[(size_t)(b0 + bbf) * 4 + o] = acc;
  }
}

extern "C" void kernel_launch(void* const* d_in, const int* in_sizes, int n_in,
                              void* d_out, int out_size, void* d_ws, size_t ws_size,
                              hipStream_t stream) {
  const float* x    = (const float*)d_in[0];
  const float* Wih0 = (const float*)d_in[1];
  const float* Whh0 = (const float*)d_in[2];
  const float* bih0 = (const float*)d_in[3];
  const float* bhh0 = (const float*)d_in[4];
  const float* Wih1 = (const float*)d_in[5];
  const float* Whh1 = (const float*)d_in[6];
  const float* bih1 = (const float*)d_in[7];
  const float* bhh1 = (const float*)d_in[8];
  const float* Wfc  = (const float*)d_in[9];
  const float* bfc  = (const float*)d_in[10];
  (void)d_ws; (void)ws_size; (void)n_in; (void)out_size;

  const int B = in_sizes[0] / (T_SEQ * 7);   // 4096
  dim3 grid(B / MB);
  lstm_fused<<<grid, NTHREADS, 0, stream>>>(x, Wih0, Whh0, bih0, bhh0,
                                            Wih1, Whh1, bih1, bhh1, Wfc, bfc,
                                            (float*)d_out);
}

// Round 3
// 970.360 us; speedup vs baseline: 1.4522x; 1.0064x over previous
//
#include <hip/hip_runtime.h>

#define T_SEQ 512
#define HID 64
#define MB 16             // batch rows per block
#define NTHREADS 512
// A1 K-layout (compact, K ksteps 0..6; ks4,5 reuse h_hi regs vs W_lo):
//   [0,64) h1_hi  [64,128) h1_lo
//   [128,135) x_hi [135,142) x_lo [142,149) x_hi(dup) [149,160) zero
// A2 K-layout: [0,64) h1_hi [64,128) h1_lo [128,192) h2_hi [192,256) h2_lo
// Column permutation: logical weight row n = g*64 + u; wave w tile i covers
//   units u = w*8 + i*4 + (l15>>2), gate g = l15&3  -> all 4 gates of a unit
//   live in one wave's C-fragment -> in-wave 4x4 transpose, no gates LDS.
#define A1STR 168   // shorts (84 dwords)
#define A2STR 264   // shorts (132 dwords)

typedef __attribute__((ext_vector_type(8))) short short8;
typedef __attribute__((ext_vector_type(4))) float floatx4;

__device__ __forceinline__ short f2bf(float v) {
  unsigned u = __float_as_uint(v);
  unsigned r = (u + 0x7FFFu + ((u >> 16) & 1u)) >> 16;   // RNE
  return (short)r;
}
__device__ __forceinline__ float bf2f(short b) {
  return __uint_as_float(((unsigned)(unsigned short)b) << 16);
}
__device__ __forceinline__ float rcp_(float x) { return __builtin_amdgcn_rcpf(x); }
__device__ __forceinline__ float sigm(float x) {
  return rcp_(1.f + __builtin_amdgcn_exp2f(-1.4426950408889634f * x));
}
__device__ __forceinline__ float tanh_(float x) {
  return 1.f - 2.f * rcp_(__builtin_amdgcn_exp2f(2.8853900817779268f * x) + 1.f);
}

// B1[k][n]: layer-1 concatenated weight (bf16 bits); n = weight row 0..255
__device__ __forceinline__ short w1elem(int k, int n, const float* __restrict__ Wih0,
                                        const float* __restrict__ Whh0) {
  float v; bool lo = false;
  if      (k < 64)  { v = Whh0[n*64 + k]; }
  else if (k < 128) { v = Whh0[n*64 + (k-64)]; }
  else if (k < 192) { v = Whh0[n*64 + (k-128)]; lo = true; }
  else if (k < 199) { v = Wih0[n*7 + (k-192)]; }
  else if (k < 206) { v = Wih0[n*7 + (k-199)]; }
  else if (k < 213) { v = Wih0[n*7 + (k-206)]; lo = true; }
  else return (short)0;
  short h = f2bf(v);
  if (!lo) return h;
  return f2bf(v - bf2f(h));
}
__device__ __forceinline__ short w2elem(int k, int n, const float* __restrict__ Wih1,
                                        const float* __restrict__ Whh1) {
  float v; bool lo = false;
  if      (k < 64)  { v = Wih1[n*64 + k]; }
  else if (k < 128) { v = Wih1[n*64 + (k-64)]; }
  else if (k < 192) { v = Wih1[n*64 + (k-128)]; lo = true; }
  else if (k < 256) { v = Whh1[n*64 + (k-192)]; }
  else if (k < 320) { v = Whh1[n*64 + (k-256)]; }
  else              { v = Whh1[n*64 + (k-320)]; lo = true; }
  short h = f2bf(v);
  if (!lo) return h;
  return f2bf(v - bf2f(h));
}

#define MFMA(A, B, C) __builtin_amdgcn_mfma_f32_16x16x32_bf16((A), (B), (C), 0, 0, 0)

// 4x4 transpose across 4-lane group (lane bits 0-1), regs a0..a3
#define XPOSE4(a0, a1, a2, a3, g4)                                   \
  {                                                                  \
    float s_;                                                        \
    s_ = __shfl_xor((g4 & 1) ? a0 : a1, 1);                          \
    if (g4 & 1) a0 = s_; else a1 = s_;                               \
    s_ = __shfl_xor((g4 & 1) ? a2 : a3, 1);                          \
    if (g4 & 1) a2 = s_; else a3 = s_;                               \
    s_ = __shfl_xor((g4 & 2) ? a0 : a2, 2);                          \
    if (g4 & 2) a0 = s_; else a2 = s_;                               \
    s_ = __shfl_xor((g4 & 2) ? a1 : a3, 2);                          \
    if (g4 & 2) a1 = s_; else a3 = s_;                               \
  }

__global__ __launch_bounds__(NTHREADS, 2) void lstm_fused(
    const float* __restrict__ x,
    const float* __restrict__ Wih0, const float* __restrict__ Whh0,
    const float* __restrict__ bih0, const float* __restrict__ bhh0,
    const float* __restrict__ Wih1, const float* __restrict__ Whh1,
    const float* __restrict__ bih1, const float* __restrict__ bhh1,
    const float* __restrict__ Wfc,  const float* __restrict__ bfc,
    float* __restrict__ out)
{
  __shared__ __align__(16) short A1[2][MB][A1STR];
  __shared__ __align__(16) short A2[2][MB][A2STR];
  __shared__ float h2f[MB][HID + 4];

  const int tid  = threadIdx.x;
  const int lane = tid & 63;
  const int wave = tid >> 6;
  const int l15  = lane & 15;
  const int quad = lane >> 4;
  const int g4   = l15 & 3;          // gate index within 4-lane group
  const int b0   = blockIdx.x * MB;
  const int row  = quad * 4 + g4;    // batch row this lane owns post-transpose
  const int u0   = wave * 8 + (l15 >> 2);       // tile-0 unit
  const int u1   = u0 + 4;                      // tile-1 unit

  // ---- init: zero both A-staging buffers ----
  for (int i = tid; i < 2*MB*A1STR/2; i += NTHREADS) ((unsigned*)A1)[i] = 0u;
  for (int i = tid; i < 2*MB*A2STR/2; i += NTHREADS) ((unsigned*)A2)[i] = 0u;

  // ---- per-lane biases for its (unit) columns, both tiles ----
  float b1r[2][4], b2r[2][4];
  #pragma unroll
  for (int g = 0; g < 4; ++g) {
    b1r[0][g] = bih0[g*64 + u0] + bhh0[g*64 + u0];
    b1r[1][g] = bih0[g*64 + u1] + bhh0[g*64 + u1];
    b2r[0][g] = bih1[g*64 + u0] + bhh1[g*64 + u0];
    b2r[1][g] = bih1[g*64 + u1] + bhh1[g*64 + u1];
  }

  // ---- stage x(0) into A1[0]; preload x(1) ----
  const int xb = tid / 7, xd = tid - xb * 7;
  float xcur = 0.f;
  if (tid < 112) {
    float xv = x[((size_t)(b0 + xb) * T_SEQ + 0) * 7 + xd];
    short xh = f2bf(xv); short xl = f2bf(xv - bf2f(xh));
    A1[0][xb][128 + xd] = xh; A1[0][xb][135 + xd] = xl; A1[0][xb][142 + xd] = xh;
    xcur = x[((size_t)(b0 + xb) * T_SEQ + 1) * 7 + xd];
  }

  // ---- weight B-fragments in registers; columns permuted n = g*64 + u ----
  short8 B1f[7][2];
  short8 B2f[12][2];
  #pragma unroll
  for (int i = 0; i < 2; ++i) {
    const int n = g4*64 + (i ? u1 : u0);
    #pragma unroll
    for (int ks = 0; ks < 7; ++ks) {
      short8 f;
      #pragma unroll
      for (int jj = 0; jj < 8; ++jj) f[jj] = w1elem(ks*32 + quad*8 + jj, n, Wih0, Whh0);
      B1f[ks][i] = f;
    }
    #pragma unroll
    for (int ks = 0; ks < 12; ++ks) {
      short8 f;
      #pragma unroll
      for (int jj = 0; jj < 8; ++jj) f[jj] = w2elem(ks*32 + quad*8 + jj, n, Wih1, Whh1);
      B2f[ks][i] = f;
    }
  }
  __syncthreads();

  float c1[2] = {0.f, 0.f}, c2[2] = {0.f, 0.f};
  float xnext = 0.f;

  // Pipelined: iteration it does GEMM1(it) and GEMM2(it-1); ONE barrier/iter.
  for (int it = 0; it <= T_SEQ; ++it) {
    const int cur = it & 1, nxt = cur ^ 1;
    if (tid < 112 && it + 2 < T_SEQ)
      xnext = x[((size_t)(b0 + xb) * T_SEQ + (it + 2)) * 7 + xd];

    floatx4 p1[2], p2[2];
    // ---- GEMM1(it): gates1 = [h1(it-1)|x(it)] x W1 ----
    if (it < T_SEQ) {
      short8 af0 = *(const short8*)&A1[cur][l15][      quad*8];
      short8 af1 = *(const short8*)&A1[cur][l15][ 32 + quad*8];
      short8 af2 = *(const short8*)&A1[cur][l15][ 64 + quad*8];
      short8 af3 = *(const short8*)&A1[cur][l15][ 96 + quad*8];
      short8 af6 = *(const short8*)&A1[cur][l15][128 + quad*8];
      #pragma unroll
      for (int i = 0; i < 2; ++i) {
        floatx4 a = {0.f,0.f,0.f,0.f};
        a = MFMA(af0, B1f[0][i], a);
        a = MFMA(af1, B1f[1][i], a);
        a = MFMA(af2, B1f[2][i], a);   // h_lo x W_hi
        a = MFMA(af3, B1f[3][i], a);
        a = MFMA(af0, B1f[4][i], a);   // h_hi x W_lo
        a = MFMA(af1, B1f[5][i], a);
        a = MFMA(af6, B1f[6][i], a);   // x block
        p1[i] = a;
      }
    }
    // ---- GEMM2(it-1): gates2 = [h1(it-1)|h2(it-2)] x W2 ----
    if (it >= 1) {
      short8 g0 = *(const short8*)&A2[cur][l15][      quad*8];
      short8 g1 = *(const short8*)&A2[cur][l15][ 32 + quad*8];
      short8 g2 = *(const short8*)&A2[cur][l15][ 64 + quad*8];
      short8 g3 = *(const short8*)&A2[cur][l15][ 96 + quad*8];
      short8 g4r= *(const short8*)&A2[cur][l15][128 + quad*8];
      short8 g5 = *(const short8*)&A2[cur][l15][160 + quad*8];
      short8 g6 = *(const short8*)&A2[cur][l15][192 + quad*8];
      short8 g7 = *(const short8*)&A2[cur][l15][224 + quad*8];
      #pragma unroll
      for (int i = 0; i < 2; ++i) {
        floatx4 a = {0.f,0.f,0.f,0.f};
        a = MFMA(g0, B2f[0][i],  a);
        a = MFMA(g1, B2f[1][i],  a);
        a = MFMA(g2, B2f[2][i],  a);   // h1_lo x W_hi
        a = MFMA(g3, B2f[3][i],  a);
        a = MFMA(g0, B2f[4][i],  a);   // h1_hi x W_lo
        a = MFMA(g1, B2f[5][i],  a);
        a = MFMA(g4r,B2f[6][i],  a);   // h2_hi x W_hi
        a = MFMA(g5, B2f[7][i],  a);
        a = MFMA(g6, B2f[8][i],  a);   // h2_lo x W_hi
        a = MFMA(g7, B2f[9][i],  a);
        a = MFMA(g4r,B2f[10][i], a);   // h2_hi x W_lo
        a = MFMA(g5, B2f[11][i], a);
        p2[i] = a;
      }
    }

    // ---- elementwise layer 1 (in-wave transpose, no barrier needed) ----
    if (it < T_SEQ) {
      #pragma unroll
      for (int i = 0; i < 2; ++i) {
        float a0 = p1[i][0], a1 = p1[i][1], a2 = p1[i][2], a3 = p1[i][3];
        XPOSE4(a0, a1, a2, a3, g4);
        float iv = sigm(a0 + b1r[i][0]);
        float fv = sigm(a1 + b1r[i][1]);
        float gv = tanh_(a2 + b1r[i][2]);
        float ov = sigm(a3 + b1r[i][3]);
        c1[i] = fv * c1[i] + iv * gv;
        float h = ov * tanh_(c1[i]);
        short hh = f2bf(h); short hl = f2bf(h - bf2f(hh));
        const int u = i ? u1 : u0;
        A1[nxt][row][u]      = hh;  A1[nxt][row][64 + u] = hl;
        A2[nxt][row][u]      = hh;  A2[nxt][row][64 + u] = hl;
      }
    }
    // ---- elementwise layer 2 ----
    if (it >= 1) {
      #pragma unroll
      for (int i = 0; i < 2; ++i) {
        float a0 = p2[i][0], a1 = p2[i][1], a2 = p2[i][2], a3 = p2[i][3];
        XPOSE4(a0, a1, a2, a3, g4);
        float iv = sigm(a0 + b2r[i][0]);
        float fv = sigm(a1 + b2r[i][1]);
        float gv = tanh_(a2 + b2r[i][2]);
        float ov = sigm(a3 + b2r[i][3]);
        c2[i] = fv * c2[i] + iv * gv;
        float h = ov * tanh_(c2[i]);
        const int u = i ? u1 : u0;
        if (it == T_SEQ) h2f[row][u] = h;
        short hh = f2bf(h); short hl = f2bf(h - bf2f(hh));
        A2[nxt][row][128 + u] = hh;  A2[nxt][row][192 + u] = hl;
      }
    }
    if (tid < 112 && it + 1 < T_SEQ) {   // stage x(it+1) into next buffer
      short xh = f2bf(xcur); short xl = f2bf(xcur - bf2f(xh));
      A1[nxt][xb][128 + xd] = xh; A1[nxt][xb][135 + xd] = xl; A1[nxt][xb][142 + xd] = xh;
      xcur = xnext;
    }
    __syncthreads();
  }

  // ---- final FC: out[b,o] = h2(T-1)[b,:] . Wfc[o,:] + bfc[o] ----
  if (tid < MB * 4) {
    int bbf = tid >> 2, o = tid & 3;
    float acc = bfc[o];
    #pragma unroll 8
    for (int k = 0; k < HID; ++k) acc += h2f[bbf][k] * Wfc[o*HID + k];
    out[(size_t)(b0 + bbf) * 4 + o] = acc;
  }
}

extern "C" void kernel_launch(void* const* d_in, const int* in_sizes, int n_in,
                              void* d_out, int out_size, void* d_ws, size_t ws_size,
                              hipStream_t stream) {
  const float* x    = (const float*)d_in[0];
  const float* Wih0 = (const float*)d_in[1];
  const float* Whh0 = (const float*)d_in[2];
  const float* bih0 = (const float*)d_in[3];
  const float* bhh0 = (const float*)d_in[4];
  const float* Wih1 = (const float*)d_in[5];
  const float* Whh1 = (const float*)d_in[6];
  const float* bih1 = (const float*)d_in[7];
  const float* bhh1 = (const float*)d_in[8];
  const float* Wfc  = (const float*)d_in[9];
  const float* bfc  = (const float*)d_in[10];
  (void)d_ws; (void)ws_size; (void)n_in; (void)out_size;

  const int B = in_sizes[0] / (T_SEQ * 7);   // 4096
  dim3 grid(B / MB);
  lstm_fused<<<grid, NTHREADS, 0, stream>>>(x, Wih0, Whh0, bih0, bhh0,
                                            Wih1, Whh1, bih1, bhh1, Wfc, bfc,
                                            (float*)d_out);
}

// Round 5
// 843.531 us; speedup vs baseline: 1.6705x; 1.1504x over previous
//
#include <hip/hip_runtime.h>

#define T_SEQ 512
#define HID 64
#define MB 16             // batch rows per block
#define NTHREADS 1024     // 16 waves, 4/SIMD: phase overlap across waves
// A1 K-layout: [0,64) h1_hi  [64,128) h1_lo  [128,135) x_hi [135,142) x_lo
//              [142,149) x_hi(dup) [149,160) zero
// A2 K-layout: [0,64) h2_hi  [64,128) h2_lo   (h1 ksteps of GEMM2 reuse A1 regs)
// Column permutation: weight row n = g*64 + u; wave w covers units
//   u = w*4 + (l15>>2), gate g = l15&3 -> 16 cols/wave, one 16x16 tile.
#define A1STR 168   // shorts (84 dw, bank step 20: 2-way only)
#define A2STR 136   // shorts (68 dw, bank step 4: 2-way only)

typedef __attribute__((ext_vector_type(8))) short short8;
typedef __attribute__((ext_vector_type(4))) float floatx4;

#define LOG2E 1.4426950408889634f

__device__ __forceinline__ short f2bf(float v) {           // round-half-up (cheap)
  return (short)((__float_as_uint(v) + 0x8000u) >> 16);
}
__device__ __forceinline__ float bf2f(short b) {
  return __uint_as_float(((unsigned)(unsigned short)b) << 16);
}
// RNE variant for weight prep (once)
__device__ __forceinline__ short f2bf_rne(float v) {
  unsigned u = __float_as_uint(v);
  return (short)((u + 0x7FFFu + ((u >> 16) & 1u)) >> 16);
}
__device__ __forceinline__ float rcp_(float x) { return __builtin_amdgcn_rcpf(x); }
__device__ __forceinline__ float sigm(float a) {           // bias pre-added
  return rcp_(1.f + __builtin_amdgcn_exp2f(-LOG2E * a));
}
__device__ __forceinline__ float tanh_(float y) {
  return 1.f - 2.f * rcp_(__builtin_amdgcn_exp2f((2.f * LOG2E) * y) + 1.f);
}

__device__ __forceinline__ short w1elem(int k, int n, const float* __restrict__ Wih0,
                                        const float* __restrict__ Whh0) {
  float v; bool lo = false;
  if      (k < 64)  { v = Whh0[n*64 + k]; }
  else if (k < 128) { v = Whh0[n*64 + (k-64)]; }
  else if (k < 192) { v = Whh0[n*64 + (k-128)]; lo = true; }
  else if (k < 199) { v = Wih0[n*7 + (k-192)]; }
  else if (k < 206) { v = Wih0[n*7 + (k-199)]; }
  else if (k < 213) { v = Wih0[n*7 + (k-206)]; lo = true; }
  else return (short)0;
  short h = f2bf_rne(v);
  if (!lo) return h;
  return f2bf_rne(v - bf2f(h));
}
__device__ __forceinline__ short w2elem(int k, int n, const float* __restrict__ Wih1,
                                        const float* __restrict__ Whh1) {
  float v; bool lo = false;
  if      (k < 64)  { v = Wih1[n*64 + k]; }
  else if (k < 128) { v = Wih1[n*64 + (k-64)]; }
  else if (k < 192) { v = Wih1[n*64 + (k-128)]; lo = true; }
  else if (k < 256) { v = Whh1[n*64 + (k-192)]; }
  else if (k < 320) { v = Whh1[n*64 + (k-256)]; }
  else              { v = Whh1[n*64 + (k-320)]; lo = true; }
  short h = f2bf_rne(v);
  if (!lo) return h;
  return f2bf_rne(v - bf2f(h));
}

#define MFMA(A, B, C) __builtin_amdgcn_mfma_f32_16x16x32_bf16((A), (B), (C), 0, 0, 0)

// 4x4 transpose across lane bits 0-1
#define XPOSE4(a0, a1, a2, a3, g4)                                   \
  {                                                                  \
    float s_;                                                        \
    s_ = __shfl_xor((g4 & 1) ? a0 : a1, 1);                          \
    if (g4 & 1) a0 = s_; else a1 = s_;                               \
    s_ = __shfl_xor((g4 & 1) ? a2 : a3, 1);                          \
    if (g4 & 1) a2 = s_; else a3 = s_;                               \
    s_ = __shfl_xor((g4 & 2) ? a0 : a2, 2);                          \
    if (g4 & 2) a0 = s_; else a2 = s_;                               \
    s_ = __shfl_xor((g4 & 2) ? a1 : a3, 2);                          \
    if (g4 & 2) a1 = s_; else a3 = s_;                               \
  }

__global__ __launch_bounds__(NTHREADS, 4) void lstm_fused(
    const float* __restrict__ x,
    const float* __restrict__ Wih0, const float* __restrict__ Whh0,
    const float* __restrict__ bih0, const float* __restrict__ bhh0,
    const float* __restrict__ Wih1, const float* __restrict__ Whh1,
    const float* __restrict__ bih1, const float* __restrict__ bhh1,
    const float* __restrict__ Wfc,  const float* __restrict__ bfc,
    float* __restrict__ out)
{
  __shared__ __align__(16) short A1[2][MB][A1STR];
  __shared__ __align__(16) short A2[2][MB][A2STR];
  __shared__ float h2f[MB][HID + 4];

  const int tid  = threadIdx.x;
  const int lane = tid & 63;
  const int wave = tid >> 6;         // 0..15
  const int l15  = lane & 15;
  const int quad = lane >> 4;
  const int g4   = l15 & 3;          // gate index within 4-lane group
  const int b0   = blockIdx.x * MB;
  const int row  = quad * 4 + g4;    // batch row this lane owns post-transpose
  const int u0   = wave * 4 + (l15 >> 2);   // unit this lane owns
  const int n    = g4 * 64 + u0;            // weight row (permuted column)

  // ---- init: zero both A-staging buffers ----
  for (int i = tid; i < 2*MB*A1STR/2; i += NTHREADS) ((unsigned*)A1)[i] = 0u;
  for (int i = tid; i < 2*MB*A2STR/2; i += NTHREADS) ((unsigned*)A2)[i] = 0u;

  // ---- per-lane bias for its column (pre-transpose) ----
  const float bc1 = bih0[n] + bhh0[n];
  const float bc2 = bih1[n] + bhh1[n];

  // ---- stage x(0) into A1[0]; preload x(1) ----
  const int xb = tid / 7, xd = tid - xb * 7;
  float xcur = 0.f;
  if (tid < 112) {
    float xv = x[((size_t)(b0 + xb) * T_SEQ + 0) * 7 + xd];
    short xh = f2bf(xv); short xl = f2bf(xv - bf2f(xh));
    A1[0][xb][128 + xd] = xh; A1[0][xb][135 + xd] = xl; A1[0][xb][142 + xd] = xh;
    xcur = x[((size_t)(b0 + xb) * T_SEQ + 1) * 7 + xd];
  }

  // ---- weight B-fragments in registers (one 16-col tile per wave) ----
  short8 B1f[7];
  short8 B2f[12];
  #pragma unroll
  for (int ks = 0; ks < 7; ++ks) {
    short8 f;
    #pragma unroll
    for (int jj = 0; jj < 8; ++jj) f[jj] = w1elem(ks*32 + quad*8 + jj, n, Wih0, Whh0);
    B1f[ks] = f;
  }
  #pragma unroll
  for (int ks = 0; ks < 12; ++ks) {
    short8 f;
    #pragma unroll
    for (int jj = 0; jj < 8; ++jj) f[jj] = w2elem(ks*32 + quad*8 + jj, n, Wih1, Whh1);
    B2f[ks] = f;
  }
  __syncthreads();

  float c1 = 0.f, c2 = 0.f;
  float xnext = 0.f;

  // Pipelined: iter it does GEMM1(it) and GEMM2(it-1); ONE barrier/iter.
  for (int it = 0; it <= T_SEQ; ++it) {
    const int cur = it & 1, nxt = cur ^ 1;
    if (tid < 112 && it + 2 < T_SEQ)
      xnext = x[((size_t)(b0 + xb) * T_SEQ + (it + 2)) * 7 + xd];

    floatx4 p1, p2;
    // h1 fragments: ALWAYS loaded — GEMM2 consumes them at it==T_SEQ too
    // (R4 bug: these were inside the it<T_SEQ guard -> stale regs at tail).
    short8 af0 = *(const short8*)&A1[cur][l15][      quad*8];
    short8 af1 = *(const short8*)&A1[cur][l15][ 32 + quad*8];
    short8 af2 = *(const short8*)&A1[cur][l15][ 64 + quad*8];
    short8 af3 = *(const short8*)&A1[cur][l15][ 96 + quad*8];
    // ---- GEMM1(it): gates1 = [h1(it-1)|x(it)] x W1 (bias in acc init) ----
    if (it < T_SEQ) {
      short8 af6 = *(const short8*)&A1[cur][l15][128 + quad*8];
      floatx4 a = {bc1, bc1, bc1, bc1};
      a = MFMA(af0, B1f[0], a);
      a = MFMA(af1, B1f[1], a);
      a = MFMA(af2, B1f[2], a);   // h_lo x W_hi
      a = MFMA(af3, B1f[3], a);
      a = MFMA(af0, B1f[4], a);   // h_hi x W_lo
      a = MFMA(af1, B1f[5], a);
      a = MFMA(af6, B1f[6], a);   // x block
      p1 = a;
    }
    // ---- GEMM2(it-1): gates2 = [h1(it-1)|h2(it-2)] x W2 ----
    if (it >= 1) {
      short8 g4r = *(const short8*)&A2[cur][l15][      quad*8];
      short8 g5  = *(const short8*)&A2[cur][l15][ 32 + quad*8];
      short8 g6  = *(const short8*)&A2[cur][l15][ 64 + quad*8];
      short8 g7  = *(const short8*)&A2[cur][l15][ 96 + quad*8];
      floatx4 a = {bc2, bc2, bc2, bc2};
      a = MFMA(af0, B2f[0],  a);   // h1_hi x W_hi
      a = MFMA(af1, B2f[1],  a);
      a = MFMA(af2, B2f[2],  a);   // h1_lo x W_hi
      a = MFMA(af3, B2f[3],  a);
      a = MFMA(af0, B2f[4],  a);   // h1_hi x W_lo
      a = MFMA(af1, B2f[5],  a);
      a = MFMA(g4r, B2f[6],  a);   // h2_hi x W_hi
      a = MFMA(g5,  B2f[7],  a);
      a = MFMA(g6,  B2f[8],  a);   // h2_lo x W_hi
      a = MFMA(g7,  B2f[9],  a);
      a = MFMA(g4r, B2f[10], a);   // h2_hi x W_lo
      a = MFMA(g5,  B2f[11], a);
      p2 = a;
    }

    // ---- elementwise layer 1 ----
    if (it < T_SEQ) {
      float a0 = p1[0], a1 = p1[1], a2 = p1[2], a3 = p1[3];
      XPOSE4(a0, a1, a2, a3, g4);
      float iv = sigm(a0), fv = sigm(a1), gv = tanh_(a2), ov = sigm(a3);
      c1 = fv * c1 + iv * gv;
      float h = ov * tanh_(c1);
      short hh = f2bf(h); short hl = f2bf(h - bf2f(hh));
      A1[nxt][row][u0]      = hh;
      A1[nxt][row][64 + u0] = hl;
    }
    // ---- elementwise layer 2 ----
    if (it >= 1) {
      float a0 = p2[0], a1 = p2[1], a2 = p2[2], a3 = p2[3];
      XPOSE4(a0, a1, a2, a3, g4);
      float iv = sigm(a0), fv = sigm(a1), gv = tanh_(a2), ov = sigm(a3);
      c2 = fv * c2 + iv * gv;
      float h = ov * tanh_(c2);
      if (it == T_SEQ) h2f[row][u0] = h;
      short hh = f2bf(h); short hl = f2bf(h - bf2f(hh));
      A2[nxt][row][u0]      = hh;
      A2[nxt][row][64 + u0] = hl;
    }
    if (tid < 112 && it + 1 < T_SEQ) {   // stage x(it+1), loaded one iter ago
      short xh = f2bf(xcur); short xl = f2bf(xcur - bf2f(xh));
      A1[nxt][xb][128 + xd] = xh; A1[nxt][xb][135 + xd] = xl; A1[nxt][xb][142 + xd] = xh;
      xcur = xnext;
    }
    __syncthreads();
  }

  // ---- final FC: out[b,o] = h2(T-1)[b,:] . Wfc[o,:] + bfc[o] ----
  if (tid < MB * 4) {
    int bbf = tid >> 2, o = tid & 3;
    float acc = bfc[o];
    #pragma unroll 8
    for (int k = 0; k < HID; ++k) acc += h2f[bbf][k] * Wfc[o*HID + k];
    out[(size_t)(b0 + bbf) * 4 + o] = acc;
  }
}

extern "C" void kernel_launch(void* const* d_in, const int* in_sizes, int n_in,
                              void* d_out, int out_size, void* d_ws, size_t ws_size,
                              hipStream_t stream) {
  const float* x    = (const float*)d_in[0];
  const float* Wih0 = (const float*)d_in[1];
  const float* Whh0 = (const float*)d_in[2];
  const float* bih0 = (const float*)d_in[3];
  const float* bhh0 = (const float*)d_in[4];
  const float* Wih1 = (const float*)d_in[5];
  const float* Whh1 = (const float*)d_in[6];
  const float* bih1 = (const float*)d_in[7];
  const float* bhh1 = (const float*)d_in[8];
  const float* Wfc  = (const float*)d_in[9];
  const float* bfc  = (const float*)d_in[10];
  (void)d_ws; (void)ws_size; (void)n_in; (void)out_size;

  const int B = in_sizes[0] / (T_SEQ * 7);   // 4096
  dim3 grid(B / MB);
  lstm_fused<<<grid, NTHREADS, 0, stream>>>(x, Wih0, Whh0, bih0, bhh0,
                                            Wih1, Whh1, bih1, bhh1, Wfc, bfc,
                                            (float*)d_out);
}